// Round 1
// baseline (438.699 us; speedup 1.0000x reference)
//
#include <hip/hip_runtime.h>
#include <cstdint>
#include <cstddef>

typedef __attribute__((ext_vector_type(8))) short bf8_t;   // 8 x bf16 bits
typedef __attribute__((ext_vector_type(4))) float f4_t;

#define DEVFN static __device__ __forceinline__
#define MFMA16(a, b, c) __builtin_amdgcn_mfma_f32_16x16x32_bf16(a, b, c, 0, 0, 0)

constexpr float kScale = 0.03608439182435161f;  // 768^-0.5 (C, not D!)

DEVFN short f2bs(float f) {  // f32 -> bf16 bits, RNE
  uint32_t u = __builtin_bit_cast(uint32_t, f);
  u = (u + 0x7FFFu + ((u >> 16) & 1u)) >> 16;
  return (short)(uint16_t)u;
}

// ---------------------------------------------------------------- cvt x->bf16
__global__ __launch_bounds__(256) void cvt_f32_bf16(const float* __restrict__ in,
                                                    short* __restrict__ out) {
  int i = blockIdx.x * 256 + threadIdx.x;          // one bf8 chunk per thread
  const f4_t* p = (const f4_t*)in + (size_t)i * 2;
  f4_t a = p[0], b = p[1];
  bf8_t h;
  h[0] = f2bs(a[0]); h[1] = f2bs(a[1]); h[2] = f2bs(a[2]); h[3] = f2bs(a[3]);
  h[4] = f2bs(b[0]); h[5] = f2bs(b[1]); h[6] = f2bs(b[2]); h[7] = f2bs(b[3]);
  *((bf8_t*)out + i) = h;
}

// ------------------------------------------------- weight transpose + convert
// w [K][N] f32  ->  wT [N][K] bf16
__global__ void transpose_cvt(const float* __restrict__ w, short* __restrict__ wT,
                              int K, int N) {
  __shared__ float tile[32][33];
  int n0 = blockIdx.x << 5, k0 = blockIdx.y << 5;
  int tx = threadIdx.x, ty = threadIdx.y;          // (32, 8)
#pragma unroll
  for (int i = 0; i < 4; ++i)
    tile[ty * 4 + i][tx] = w[(size_t)(k0 + ty * 4 + i) * N + n0 + tx];
  __syncthreads();
#pragma unroll
  for (int i = 0; i < 4; ++i)
    wT[(size_t)(n0 + ty * 4 + i) * K + k0 + tx] = f2bs(tile[tx][ty * 4 + i]);
}

// ------------------------------------------------------------------ bf16 GEMM
// C[M][N] = A[M][K] @ Bt[N][K]^T + bias.  128x128 tile, BK=64, 4 waves (2x2),
// each wave 64x64 via 4x4 grid of 16x16x32 MFMA. LDS XOR-swizzle (slot^(row&7)).
// EPI 0: scatter q/k bf16 [B,H,T,D] + v bf16 transposed [B,H,D,T]
// EPI 1: fp32 out
template <int EPI>
__global__ __launch_bounds__(256) void gemm_bf16(
    const short* __restrict__ A, const short* __restrict__ Bt,
    const float* __restrict__ bias, float* __restrict__ outF,
    short* __restrict__ qb, short* __restrict__ kb, short* __restrict__ vtb,
    int Mdim, int Ndim, int Kdim) {
  __shared__ short As[128 * 64];
  __shared__ short Bs[128 * 64];
  const int m0 = blockIdx.y << 7, n0 = blockIdx.x << 7;
  const int tid = threadIdx.x;
  const int lane = tid & 63, wid = tid >> 6;
  const int wr = wid >> 1, wc = wid & 1;
  const int g = lane >> 4, cl = lane & 15;

  f4_t acc[4][4];
#pragma unroll
  for (int mi = 0; mi < 4; ++mi)
#pragma unroll
    for (int ni = 0; ni < 4; ++ni) acc[mi][ni] = (f4_t){0.f, 0.f, 0.f, 0.f};

  const int nk = Kdim >> 6;
  for (int ks = 0; ks < nk; ++ks) {
    const int k0 = ks << 6;
#pragma unroll
    for (int i = 0; i < 4; ++i) {                  // stage 128x64 A and B tiles
      int idx = tid + (i << 8);
      int row = idx >> 3, c8 = idx & 7;
      int off = (row << 6) + ((c8 ^ (row & 7)) << 3);
      *(bf8_t*)&As[off] = *(const bf8_t*)(A + (size_t)(m0 + row) * Kdim + k0 + (c8 << 3));
      *(bf8_t*)&Bs[off] = *(const bf8_t*)(Bt + (size_t)(n0 + row) * Kdim + k0 + (c8 << 3));
    }
    __syncthreads();
#pragma unroll
    for (int kk = 0; kk < 2; ++kk) {
      bf8_t af[4], bfv[4];
#pragma unroll
      for (int mi = 0; mi < 4; ++mi) {
        int lrow = (wr << 6) + (mi << 4) + cl;
        af[mi] = *(const bf8_t*)&As[(lrow << 6) + ((((kk << 2) + g) ^ (lrow & 7)) << 3)];
      }
#pragma unroll
      for (int ni = 0; ni < 4; ++ni) {
        int lrow = (wc << 6) + (ni << 4) + cl;
        bfv[ni] = *(const bf8_t*)&Bs[(lrow << 6) + ((((kk << 2) + g) ^ (lrow & 7)) << 3)];
      }
#pragma unroll
      for (int mi = 0; mi < 4; ++mi)
#pragma unroll
        for (int ni = 0; ni < 4; ++ni)
          acc[mi][ni] = MFMA16(af[mi], bfv[ni], acc[mi][ni]);
    }
    __syncthreads();
  }

  // epilogue.  C/D layout: col = lane&15, row = (lane>>4)*4 + r  [m89-verified]
#pragma unroll
  for (int ni = 0; ni < 4; ++ni) {
    const int n = n0 + (wc << 6) + (ni << 4) + cl;
    const float bv = bias[n];
#pragma unroll
    for (int mi = 0; mi < 4; ++mi) {
#pragma unroll
      for (int r = 0; r < 4; ++r) {
        const int m = m0 + (wr << 6) + (mi << 4) + (g << 2) + r;
        float val = acc[mi][ni][r] + bv;
        if constexpr (EPI == 0) {
          const int b = m >> 11, t = m & 2047;
          const int sec = n0 / 768;                // block-uniform section
          const int nn = n - sec * 768;
          const int hh = nn >> 6, d = nn & 63;
          const size_t bh = (size_t)(b * 12 + hh);
          const short hv = f2bs(val);
          if (sec == 0)      qb[bh * 131072 + (size_t)t * 64 + d] = hv;
          else if (sec == 1) kb[bh * 131072 + (size_t)t * 64 + d] = hv;
          else               vtb[bh * 131072 + (size_t)d * 2048 + t] = hv;
        } else {
          outF[(size_t)m * 768 + n] = val;
        }
      }
    }
  }
}

// ---------------------------------------------------------- flash attention
// 1 wave per 16 q-rows. K/V streamed from global (L2-resident per head).
// QK^T: A=Q rows, B=K rows (both k-contig over D). Online softmax per q-row
// (rows live in lane-groups; reduce over 16 cols via shfl_xor 1/2/4/8).
// P -> per-wave LDS [16][56] -> one b128 A-frag read -> PV with Vt [D][T].
__global__ __launch_bounds__(256) void attn_fwd(const short* __restrict__ Q,
                                                const short* __restrict__ K,
                                                const short* __restrict__ Vt,
                                                short* __restrict__ O) {
  __shared__ short P_lds[4][16 * 56];
  const int tid = threadIdx.x;
  const int lane = tid & 63, wid = tid >> 6;
  const int w = (blockIdx.x << 2) + wid;
  const int qt = w & 127, bh = w >> 7;
  const int q0 = qt << 4;
  const int g = lane >> 4, cl = lane & 15;

  const short* Qb = Q + (size_t)bh * 131072;
  const short* Kb = K + (size_t)bh * 131072;
  const short* Vb = Vt + (size_t)bh * 131072;

  const bf8_t aq0 = *(const bf8_t*)(Qb + (q0 + cl) * 64 + (g << 3));
  const bf8_t aq1 = *(const bf8_t*)(Qb + (q0 + cl) * 64 + 32 + (g << 3));

  f4_t o[4];
#pragma unroll
  for (int dt = 0; dt < 4; ++dt) o[dt] = (f4_t){0.f, 0.f, 0.f, 0.f};
  float m_run[4] = {-1e30f, -1e30f, -1e30f, -1e30f};
  float l_run[4] = {0.f, 0.f, 0.f, 0.f};

  short* P = P_lds[wid];
  const int nchunk = ((q0 + 15) >> 5) + 1;

  for (int ch = 0; ch < nchunk; ++ch) {
    const int kc = ch << 5;
    f4_t s[2];
#pragma unroll
    for (int j = 0; j < 2; ++j) {
      const short* Kr = Kb + (kc + (j << 4) + cl) * 64 + (g << 3);
      bf8_t bk0 = *(const bf8_t*)Kr;
      bf8_t bk1 = *(const bf8_t*)(Kr + 32);
      f4_t z = (f4_t){0.f, 0.f, 0.f, 0.f};
      z = MFMA16(aq0, bk0, z);
      z = MFMA16(aq1, bk1, z);
      s[j] = z * kScale;
    }
    if (kc + 31 > q0) {                            // causal mask (uniform branch)
#pragma unroll
      for (int j = 0; j < 2; ++j) {
        const int kidx = kc + (j << 4) + cl;
#pragma unroll
        for (int r = 0; r < 4; ++r)
          if (kidx > q0 + (g << 2) + r) s[j][r] = -1e30f;
      }
    }
    float pm[4], alpha[4];
#pragma unroll
    for (int r = 0; r < 4; ++r) {
      float v = fmaxf(s[0][r], s[1][r]);
#pragma unroll
      for (int msk = 1; msk < 16; msk <<= 1) v = fmaxf(v, __shfl_xor(v, msk, 64));
      pm[r] = v;
    }
#pragma unroll
    for (int r = 0; r < 4; ++r) {
      float mn = fmaxf(m_run[r], pm[r]);
      alpha[r] = __expf(m_run[r] - mn);
      m_run[r] = mn;
    }
#pragma unroll
    for (int j = 0; j < 2; ++j)
#pragma unroll
      for (int r = 0; r < 4; ++r) s[j][r] = __expf(s[j][r] - m_run[r]);
#pragma unroll
    for (int r = 0; r < 4; ++r) {
      float v = s[0][r] + s[1][r];
#pragma unroll
      for (int msk = 1; msk < 16; msk <<= 1) v += __shfl_xor(v, msk, 64);
      l_run[r] = l_run[r] * alpha[r] + v;
    }
    // P (bf16) -> LDS [q][k], pad 56 elems/row
#pragma unroll
    for (int j = 0; j < 2; ++j)
#pragma unroll
      for (int r = 0; r < 4; ++r)
        P[((g << 2) + r) * 56 + (j << 4) + cl] = f2bs(s[j][r]);
    asm volatile("" ::: "memory");                 // keep DS program order
    const bf8_t pa = *(const bf8_t*)&P[cl * 56 + (g << 3)];
    asm volatile("" ::: "memory");
#pragma unroll
    for (int dt = 0; dt < 4; ++dt) {
      bf8_t bv = *(const bf8_t*)(Vb + ((dt << 4) + cl) * 2048 + kc + (g << 3));
      f4_t oo = o[dt];
#pragma unroll
      for (int r = 0; r < 4; ++r) oo[r] *= alpha[r];
      o[dt] = MFMA16(pa, bv, oo);
    }
  }
  // write O[b][t][h*64+d] bf16
  const int b = bh / 12, hh = bh % 12;
  short* Ob = O + (size_t)b * 2048 * 768 + hh * 64;
#pragma unroll
  for (int dt = 0; dt < 4; ++dt)
#pragma unroll
    for (int r = 0; r < 4; ++r) {
      const int q = q0 + (g << 2) + r;
      Ob[(size_t)q * 768 + (dt << 4) + cl] = f2bs(o[dt][r] / l_run[r]);
    }
}

// ------------------------------------------------------------------- launch
extern "C" void kernel_launch(void* const* d_in, const int* in_sizes, int n_in,
                              void* d_out, int out_size, void* d_ws, size_t ws_size,
                              hipStream_t stream) {
  const float* x      = (const float*)d_in[0];
  const float* w_attn = (const float*)d_in[1];
  const float* b_attn = (const float*)d_in[2];
  const float* w_proj = (const float*)d_in[3];
  const float* b_proj = (const float*)d_in[4];
  float* out = (float*)d_out;

  const size_t QSZ = (size_t)4 * 12 * 2048 * 64;   // 6291456 elems
  short* ws  = (short*)d_ws;
  short* qb  = ws;
  short* kb  = qb + QSZ;
  short* vtb = kb + QSZ;
  short* xb  = vtb + QSZ;                          // x bf16; reused as O after GEMM1
  short* ob  = xb;                                 // alias (GEMM1 done before attn)
  short* wat = xb + QSZ;                           // w_attn^T bf16 [2304][768]
  short* wpt = wat + (size_t)2304 * 768;           // w_proj^T bf16 [768][768]

  cvt_f32_bf16<<<3072, 256, 0, stream>>>(x, xb);
  transpose_cvt<<<dim3(72, 24), dim3(32, 8), 0, stream>>>(w_attn, wat, 768, 2304);
  transpose_cvt<<<dim3(24, 24), dim3(32, 8), 0, stream>>>(w_proj, wpt, 768, 768);

  gemm_bf16<0><<<dim3(18, 64), 256, 0, stream>>>(xb, wat, b_attn, nullptr,
                                                 qb, kb, vtb, 8192, 2304, 768);
  attn_fwd<<<1536, 256, 0, stream>>>(qb, kb, vtb, ob);
  gemm_bf16<1><<<dim3(6, 64), 256, 0, stream>>>(ob, wpt, b_proj, out,
                                                nullptr, nullptr, nullptr, 8192, 768, 768);
}

// Round 3
// 206.452 us; speedup vs baseline: 2.1249x; 2.1249x over previous
//
#include <hip/hip_runtime.h>
#include <cstdint>
#include <cstddef>

typedef __attribute__((ext_vector_type(8))) short bf8_t;    // 8 x bf16 bits
typedef __attribute__((ext_vector_type(4))) float f4_t;
typedef __attribute__((ext_vector_type(16))) float f16v_t;
typedef __attribute__((ext_vector_type(2))) unsigned u2_t;
typedef __attribute__((ext_vector_type(4))) unsigned u4_t;

#define DEVFN static __device__ __forceinline__
#define MFMA16(a, b, c) __builtin_amdgcn_mfma_f32_16x16x32_bf16(a, b, c, 0, 0, 0)
#define MFMA32(a, b, c) __builtin_amdgcn_mfma_f32_32x32x16_bf16(a, b, c, 0, 0, 0)

// 768^-0.5 * log2(e): folded into Q at GEMM1 epilogue; attn uses exp2 directly.
constexpr float kQscale = 0.05205877317700523f;

DEVFN short f2bs(float f) {  // f32 -> bf16 bits, RNE
  uint32_t u = __builtin_bit_cast(uint32_t, f);
  u = (u + 0x7FFFu + ((u >> 16) & 1u)) >> 16;
  return (short)(uint16_t)u;
}

DEVFN unsigned cvtpk(float lo, float hi) {  // packed bf16(lo) | bf16(hi)<<16
  unsigned r;
  asm("v_cvt_pk_bf16_f32 %0, %1, %2" : "=v"(r) : "v"(lo), "v"(hi));
  return r;
}

DEVFN float red2_max(float v) { return fmaxf(v, __shfl_xor(v, 32, 64)); }
DEVFN float red2_sum(float v) { return v + __shfl_xor(v, 32, 64); }

// ---------------------------------------------------------------- cvt x->bf16
__global__ __launch_bounds__(256) void cvt_f32_bf16(const float* __restrict__ in,
                                                    short* __restrict__ out) {
  int i = blockIdx.x * 256 + threadIdx.x;          // one bf8 chunk per thread
  const f4_t* p = (const f4_t*)in + (size_t)i * 2;
  f4_t a = p[0], b = p[1];
  bf8_t h;
  h[0] = f2bs(a[0]); h[1] = f2bs(a[1]); h[2] = f2bs(a[2]); h[3] = f2bs(a[3]);
  h[4] = f2bs(b[0]); h[5] = f2bs(b[1]); h[6] = f2bs(b[2]); h[7] = f2bs(b[3]);
  *((bf8_t*)out + i) = h;
}

// ------------------------------------------------- weight transpose + convert
__global__ void transpose_cvt(const float* __restrict__ w, short* __restrict__ wT,
                              int K, int N) {
  __shared__ float tile[32][33];
  int n0 = blockIdx.x << 5, k0 = blockIdx.y << 5;
  int tx = threadIdx.x, ty = threadIdx.y;          // (32, 8)
#pragma unroll
  for (int i = 0; i < 4; ++i)
    tile[ty * 4 + i][tx] = w[(size_t)(k0 + ty * 4 + i) * N + n0 + tx];
  __syncthreads();
#pragma unroll
  for (int i = 0; i < 4; ++i)
    wT[(size_t)(n0 + ty * 4 + i) * K + k0 + tx] = f2bs(tile[tx][ty * 4 + i]);
}

// ------------------------------------------------------------------ bf16 GEMM
// C[M][N] = A[M][K] @ Bt[N][K]^T + bias.  128x128 tile, BK=64, 4 waves (2x2).
// EPI 0: scatter q(scaled)/k bf16 [B,H,T,D] + v bf16 transposed [B,H,D,T]
// EPI 1: fp32 out
template <int EPI>
__global__ __launch_bounds__(256) void gemm_bf16(
    const short* __restrict__ A, const short* __restrict__ Bt,
    const float* __restrict__ bias, float* __restrict__ outF,
    short* __restrict__ qb, short* __restrict__ kb, short* __restrict__ vtb,
    int Mdim, int Ndim, int Kdim) {
  __shared__ short As[128 * 64];
  __shared__ short Bs[128 * 64];
  const int m0 = blockIdx.y << 7, n0 = blockIdx.x << 7;
  const int tid = threadIdx.x;
  const int lane = tid & 63, wid = tid >> 6;
  const int wr = wid >> 1, wc = wid & 1;
  const int g = lane >> 4, cl = lane & 15;

  f4_t acc[4][4];
#pragma unroll
  for (int mi = 0; mi < 4; ++mi)
#pragma unroll
    for (int ni = 0; ni < 4; ++ni) acc[mi][ni] = (f4_t){0.f, 0.f, 0.f, 0.f};

  const int nk = Kdim >> 6;
  for (int ks = 0; ks < nk; ++ks) {
    const int k0 = ks << 6;
#pragma unroll
    for (int i = 0; i < 4; ++i) {                  // stage 128x64 A and B tiles
      int idx = tid + (i << 8);
      int row = idx >> 3, c8 = idx & 7;
      int off = (row << 6) + ((c8 ^ (row & 7)) << 3);
      *(bf8_t*)&As[off] = *(const bf8_t*)(A + (size_t)(m0 + row) * Kdim + k0 + (c8 << 3));
      *(bf8_t*)&Bs[off] = *(const bf8_t*)(Bt + (size_t)(n0 + row) * Kdim + k0 + (c8 << 3));
    }
    __syncthreads();
#pragma unroll
    for (int kk = 0; kk < 2; ++kk) {
      bf8_t af[4], bfv[4];
#pragma unroll
      for (int mi = 0; mi < 4; ++mi) {
        int lrow = (wr << 6) + (mi << 4) + cl;
        af[mi] = *(const bf8_t*)&As[(lrow << 6) + ((((kk << 2) + g) ^ (lrow & 7)) << 3)];
      }
#pragma unroll
      for (int ni = 0; ni < 4; ++ni) {
        int lrow = (wc << 6) + (ni << 4) + cl;
        bfv[ni] = *(const bf8_t*)&Bs[(lrow << 6) + ((((kk << 2) + g) ^ (lrow & 7)) << 3)];
      }
#pragma unroll
      for (int mi = 0; mi < 4; ++mi)
#pragma unroll
        for (int ni = 0; ni < 4; ++ni)
          acc[mi][ni] = MFMA16(af[mi], bfv[ni], acc[mi][ni]);
    }
    __syncthreads();
  }

  // epilogue.  C/D layout: col = lane&15, row = (lane>>4)*4 + r
#pragma unroll
  for (int ni = 0; ni < 4; ++ni) {
    const int n = n0 + (wc << 6) + (ni << 4) + cl;
    const float bv = bias[n];
#pragma unroll
    for (int mi = 0; mi < 4; ++mi) {
#pragma unroll
      for (int r = 0; r < 4; ++r) {
        const int m = m0 + (wr << 6) + (mi << 4) + (g << 2) + r;
        float val = acc[mi][ni][r] + bv;
        if constexpr (EPI == 0) {
          const int b = m >> 11, t = m & 2047;
          const int sec = n0 / 768;                // block-uniform section
          const int nn = n - sec * 768;
          const int hh = nn >> 6, d = nn & 63;
          const size_t bh = (size_t)(b * 12 + hh);
          if (sec == 0) {
            qb[bh * 131072 + (size_t)t * 64 + d] = f2bs(val * kQscale);
          } else if (sec == 1) {
            kb[bh * 131072 + (size_t)t * 64 + d] = f2bs(val);
          } else {
            vtb[bh * 131072 + (size_t)d * 2048 + t] = f2bs(val);
          }
        } else {
          outF[(size_t)m * 768 + n] = val;
        }
      }
    }
  }
}

// ---------------------------------------------------------- flash attention
// 1 wave per 32 q-rows, KVBLK=64/step, no LDS, no barriers.
// Swapped QK^T: S^T = mfma32(K_frag, Q_frag) -> col = q (lane&31),
// row = k = (r&3)+8*(r>>2)+4*hi. Softmax per q: in-lane tree + one
// __shfl_xor(32) to combine the lane pair. P^T B-frags for PV built via
// cvt_pk + 4 __shfl_xor(32) per 16-k chunk. PV: O^T = mfma32(V^T, P^T)
// with Vt [D][T]. Q pre-scaled by 768^-0.5*log2e -> exp2 directly.
__global__ __launch_bounds__(256) void attn_fwd(const short* __restrict__ Q,
                                                const short* __restrict__ K,
                                                const short* __restrict__ Vt,
                                                short* __restrict__ O) {
  const int tid = threadIdx.x;
  const int lane = tid & 63, wid = tid >> 6;
  const int blk = blockIdx.x;                      // 768 blocks
  const int bh = blk % 48;                         // same-XCD blocks share bh
  const int qtg = 15 - blk / 48;                   // long tiles first
  const int qt = (qtg << 2) + wid;
  const int q0 = qt << 5;
  const int col = lane & 31, hi = lane >> 5;

  const short* Qb = Q + (size_t)bh * 131072;
  const short* Kb = K + (size_t)bh * 131072;
  const short* Vb = Vt + (size_t)bh * 131072;

  bf8_t qf[4];                                     // Q^T B-fragments (persist)
#pragma unroll
  for (int dc = 0; dc < 4; ++dc)
    qf[dc] = *(const bf8_t*)(Qb + (size_t)(q0 + col) * 64 + dc * 16 + hi * 8);

  f16v_t o0 = {0.f,0.f,0.f,0.f,0.f,0.f,0.f,0.f,0.f,0.f,0.f,0.f,0.f,0.f,0.f,0.f};
  f16v_t o1 = o0;
  float m_ = -1e30f, l_ = 0.f;

  const int nstep = (q0 + 32 + 63) >> 6;
  for (int st = 0; st < nstep; ++st) {
    const int kc = st << 6;
    // ---- QK^T (8 MFMA): S^T for k in [kc, kc+64)
    f16v_t s0 = {0.f,0.f,0.f,0.f,0.f,0.f,0.f,0.f,0.f,0.f,0.f,0.f,0.f,0.f,0.f,0.f};
    f16v_t s1 = s0;
#pragma unroll
    for (int dc = 0; dc < 4; ++dc) {
      bf8_t k0 = *(const bf8_t*)(Kb + (size_t)(kc + col) * 64 + dc * 16 + hi * 8);
      bf8_t k1 = *(const bf8_t*)(Kb + (size_t)(kc + 32 + col) * 64 + dc * 16 + hi * 8);
      s0 = MFMA32(k0, qf[dc], s0);
      s1 = MFMA32(k1, qf[dc], s1);
    }
    // ---- causal mask (only on diagonal-crossing steps; wave-uniform branch)
    if (kc + 63 > q0) {
      const int qq = q0 + col;
#pragma unroll
      for (int r = 0; r < 16; ++r) {
        const int kb_ = kc + (r & 3) + 8 * (r >> 2) + 4 * hi;
        if (kb_ > qq) s0[r] = -1e30f;
        if (kb_ + 32 > qq) s1[r] = -1e30f;
      }
    }
    // ---- online softmax (tree max/sum in-lane, one shfl for partner half)
    float t16[16];
#pragma unroll
    for (int r = 0; r < 16; ++r) t16[r] = fmaxf(s0[r], s1[r]);
#pragma unroll
    for (int stp = 8; stp > 0; stp >>= 1)
#pragma unroll
      for (int r = 0; r < 8; ++r)
        if (r < stp) t16[r] = fmaxf(t16[r], t16[r + stp]);
    const float mx = red2_max(t16[0]);
    const float mn = fmaxf(m_, mx);
    const float alpha = __builtin_amdgcn_exp2f(m_ - mn);
    m_ = mn;
#pragma unroll
    for (int r = 0; r < 16; ++r) {
      s0[r] = __builtin_amdgcn_exp2f(s0[r] - mn);
      s1[r] = __builtin_amdgcn_exp2f(s1[r] - mn);
    }
#pragma unroll
    for (int r = 0; r < 16; ++r) t16[r] = s0[r] + s1[r];
#pragma unroll
    for (int stp = 8; stp > 0; stp >>= 1)
#pragma unroll
      for (int r = 0; r < 8; ++r)
        if (r < stp) t16[r] += t16[r + stp];
    l_ = l_ * alpha + red2_sum(t16[0]);
#pragma unroll
    for (int r = 0; r < 16; ++r) { o0[r] *= alpha; o1[r] *= alpha; }
    // ---- PV: assemble P^T B-frags (own words + lane^32 partner words)
    // own lane holds k-locals {c*16 + 4hi..4hi+3, c*16 + 8+4hi..8+4hi+3};
    // fragment needs k-locals {c*16 + 8hi .. 8hi+7}:
    //   hi=0: T = {w0, w1, x0, x1}   hi=1: T = {x2, x3, w2, w3}
#pragma unroll
    for (int c = 0; c < 4; ++c) {
      const int b8 = (c & 1) * 8;
      float p0, p1, p2, p3, p4, p5, p6, p7;
      if (c < 2) {
        p0 = s0[b8+0]; p1 = s0[b8+1]; p2 = s0[b8+2]; p3 = s0[b8+3];
        p4 = s0[b8+4]; p5 = s0[b8+5]; p6 = s0[b8+6]; p7 = s0[b8+7];
      } else {
        p0 = s1[b8+0]; p1 = s1[b8+1]; p2 = s1[b8+2]; p3 = s1[b8+3];
        p4 = s1[b8+4]; p5 = s1[b8+5]; p6 = s1[b8+6]; p7 = s1[b8+7];
      }
      unsigned w0 = cvtpk(p0, p1), w1 = cvtpk(p2, p3);
      unsigned w2 = cvtpk(p4, p5), w3 = cvtpk(p6, p7);
      unsigned x0 = (unsigned)__shfl_xor((int)w0, 32, 64);
      unsigned x1 = (unsigned)__shfl_xor((int)w1, 32, 64);
      unsigned x2 = (unsigned)__shfl_xor((int)w2, 32, 64);
      unsigned x3 = (unsigned)__shfl_xor((int)w3, 32, 64);
      unsigned T0 = hi ? x2 : w0;
      unsigned T1 = hi ? x3 : w1;
      unsigned T2 = hi ? w2 : x0;
      unsigned T3 = hi ? w3 : x1;
      const bf8_t pf = __builtin_bit_cast(bf8_t, (u4_t){T0, T1, T2, T3});
      bf8_t v0 = *(const bf8_t*)(Vb + (size_t)col * 2048 + kc + c * 16 + hi * 8);
      bf8_t v1 = *(const bf8_t*)(Vb + (size_t)(32 + col) * 2048 + kc + c * 16 + hi * 8);
      o0 = MFMA32(v0, pf, o0);
      o1 = MFMA32(v1, pf, o1);
    }
  }
  // ---- epilogue: O[b][t][h*64+d] bf16, d(o0) = 8*rq + 4*hi + j, d(o1) = +32
  const float rl = 1.0f / l_;
  const int b_ = bh / 12, hh = bh % 12;
  short* Op = O + (size_t)b_ * 2048 * 768 + (size_t)(q0 + col) * 768 + hh * 64;
#pragma unroll
  for (int rq = 0; rq < 4; ++rq) {
    u2_t w0, w1;
    w0[0] = cvtpk(o0[4*rq+0] * rl, o0[4*rq+1] * rl);
    w0[1] = cvtpk(o0[4*rq+2] * rl, o0[4*rq+3] * rl);
    w1[0] = cvtpk(o1[4*rq+0] * rl, o1[4*rq+1] * rl);
    w1[1] = cvtpk(o1[4*rq+2] * rl, o1[4*rq+3] * rl);
    *(u2_t*)(Op + rq * 8 + hi * 4) = w0;
    *(u2_t*)(Op + 32 + rq * 8 + hi * 4) = w1;
  }
}

// ------------------------------------------------------------------- launch
extern "C" void kernel_launch(void* const* d_in, const int* in_sizes, int n_in,
                              void* d_out, int out_size, void* d_ws, size_t ws_size,
                              hipStream_t stream) {
  const float* x      = (const float*)d_in[0];
  const float* w_attn = (const float*)d_in[1];
  const float* b_attn = (const float*)d_in[2];
  const float* w_proj = (const float*)d_in[3];
  const float* b_proj = (const float*)d_in[4];
  float* out = (float*)d_out;

  const size_t QSZ = (size_t)4 * 12 * 2048 * 64;   // 6291456 elems
  short* ws  = (short*)d_ws;
  short* qb  = ws;
  short* kb  = qb + QSZ;
  short* vtb = kb + QSZ;
  short* xb  = vtb + QSZ;                          // x bf16; reused as O after GEMM1
  short* ob  = xb;                                 // alias (GEMM1 done before attn)
  short* wat = xb + QSZ;                           // w_attn^T bf16 [2304][768]
  short* wpt = wat + (size_t)2304 * 768;           // w_proj^T bf16 [768][768]

  cvt_f32_bf16<<<3072, 256, 0, stream>>>(x, xb);
  transpose_cvt<<<dim3(72, 24), dim3(32, 8), 0, stream>>>(w_attn, wat, 768, 2304);
  transpose_cvt<<<dim3(24, 24), dim3(32, 8), 0, stream>>>(w_proj, wpt, 768, 768);

  gemm_bf16<0><<<dim3(18, 64), 256, 0, stream>>>(xb, wat, b_attn, nullptr,
                                                 qb, kb, vtb, 8192, 2304, 768);
  attn_fwd<<<768, 256, 0, stream>>>(qb, kb, vtb, ob);
  gemm_bf16<1><<<dim3(6, 64), 256, 0, stream>>>(ob, wpt, b_proj, out,
                                                nullptr, nullptr, nullptr, 8192, 768, 768);
}